// Round 2
// baseline (195.344 us; speedup 1.0000x reference)
//
#include <hip/hip_runtime.h>

typedef unsigned short u16;
typedef unsigned int   u32;
typedef __attribute__((ext_vector_type(8))) short bf8_t;   // 8 bf16 (4 VGPR)
typedef __attribute__((ext_vector_type(4))) float f4_t;

#define SEQ   1024
#define NH    16
#define DH    128
#define BATCH 4
#define MROWS 4096      // BATCH*SEQ
#define FDIM  2048      // NH*DH

__device__ __forceinline__ u16 f2bf(float f) {
  union { float f; u32 u; } v; v.f = f;
  u32 u = v.u;
  u += 0x7fffu + ((u >> 16) & 1u);   // RNE
  return (u16)(u >> 16);
}
__device__ __forceinline__ float bf2f(u16 b) {
  union { u32 u; float f; } v; v.u = ((u32)b) << 16;
  return v.f;
}

// ---------------- kernel 0: RoPE tables ------------------------------------
// Match the np reference's fp32 pipeline: ang and theta rounded to fp32,
// then cos/sin of that exact fp32 theta evaluated in fp64.
__global__ __launch_bounds__(256) void rope_tables(float* __restrict__ cosT,
                                                   float* __restrict__ sinT) {
  int i = blockIdx.x * 256 + threadIdx.x;      // 65536 = 1024*64
  int s = i >> 6, p = i & 63;
  float ef = (float)(2 * p) / 128.0f;                 // exact in fp32
  float angf = (float)pow(10000.0, (double)ef);       // ~np.power(f32) bits
  float thf  = (float)s * angf;                       // fp32 multiply like np
  double th  = (double)thf;
  cosT[i] = (float)cos(th);
  sinT[i] = (float)sin(th);
}

// ---------------- kernel A: fused QKV projection + RoPE --------------------
// q = x @ wq^T (etc), 64x64 tile, K=128 single-shot in LDS, 4 waves 2x2.
__global__ __launch_bounds__(256) void qkv_rope(
    const float* __restrict__ x,
    const float* __restrict__ wq, const float* __restrict__ wk,
    const float* __restrict__ wv,
    const float* __restrict__ cosT, const float* __restrict__ sinT,
    u16* __restrict__ qo, u16* __restrict__ ko, u16* __restrict__ vo) {
  __shared__ __align__(16) u16 a_lds[64 * 128];
  __shared__ __align__(16) u16 b_lds[64 * 128];
  const int tid = threadIdx.x;
  const int mt = blockIdx.x;            // 0..63
  const int by = blockIdx.y;            // 0..95
  const int mat = by >> 5;              // 0:q 1:k 2:v
  const int nt  = by & 31;
  const float* w = (mat == 0) ? wq : ((mat == 1) ? wk : wv);
  u16* outp      = (mat == 0) ? qo : ((mat == 1) ? ko : vo);
  const int m0 = mt * 64, n0 = nt * 64;

#pragma unroll
  for (int i = 0; i < 4; ++i) {
    int idx = tid + i * 256;            // 0..1023
    int row = idx >> 4, e0 = (idx & 15) * 8;
    const f4_t* xs = reinterpret_cast<const f4_t*>(x + (size_t)(m0 + row) * 128 + e0);
    f4_t lo = xs[0], hi = xs[1];
    bf8_t pk;
#pragma unroll
    for (int j = 0; j < 4; ++j) { pk[j] = (short)f2bf(lo[j]); pk[4 + j] = (short)f2bf(hi[j]); }
    int hw = ((row << 7) | e0) ^ ((row & 7) << 3);
    *reinterpret_cast<bf8_t*>(&a_lds[hw]) = pk;
    const f4_t* wsrc = reinterpret_cast<const f4_t*>(w + (size_t)(n0 + row) * 128 + e0);
    f4_t wlo = wsrc[0], whi = wsrc[1];
    bf8_t wk8;
#pragma unroll
    for (int j = 0; j < 4; ++j) { wk8[j] = (short)f2bf(wlo[j]); wk8[4 + j] = (short)f2bf(whi[j]); }
    *reinterpret_cast<bf8_t*>(&b_lds[hw]) = wk8;
  }
  __syncthreads();

  const int lane = tid & 63, wid = tid >> 6;
  const int wr = wid >> 1, wc = wid & 1;
  const int g = lane >> 4, c16 = lane & 15;
  f4_t acc[2][2];
#pragma unroll
  for (int a = 0; a < 2; ++a)
#pragma unroll
    for (int b = 0; b < 2; ++b) acc[a][b] = (f4_t)0.0f;

#pragma unroll
  for (int kc = 0; kc < 4; ++kc) {
    bf8_t af[2], bf_[2];
#pragma unroll
    for (int fr = 0; fr < 2; ++fr) {
      int row = wr * 32 + fr * 16 + c16;
      int hw = ((row << 7) | (kc * 32 + g * 8)) ^ ((row & 7) << 3);
      af[fr] = *reinterpret_cast<const bf8_t*>(&a_lds[hw]);
    }
#pragma unroll
    for (int fc = 0; fc < 2; ++fc) {
      int row = wc * 32 + fc * 16 + c16;
      int hw = ((row << 7) | (kc * 32 + g * 8)) ^ ((row & 7) << 3);
      bf_[fc] = *reinterpret_cast<const bf8_t*>(&b_lds[hw]);
    }
#pragma unroll
    for (int fr = 0; fr < 2; ++fr)
#pragma unroll
      for (int fc = 0; fc < 2; ++fc)
        acc[fr][fc] = __builtin_amdgcn_mfma_f32_16x16x32_bf16(af[fr], bf_[fc], acc[fr][fc], 0, 0, 0);
  }

  // epilogue: RoPE (q,k) / passthrough (v); pair via shfl_xor(1); even lanes store u32
#pragma unroll
  for (int fr = 0; fr < 2; ++fr) {
#pragma unroll
    for (int fc = 0; fc < 2; ++fc) {
      int fcol = n0 + wc * 32 + fc * 16 + c16;   // 0..2047
      int h = fcol >> 7, d = fcol & 127, p = d >> 1;
#pragma unroll
      for (int j = 0; j < 4; ++j) {
        int m = m0 + wr * 32 + fr * 16 + g * 4 + j;
        int b = m >> 10, sl = m & 1023;
        float v = acc[fr][fc][j];
        float vx = __shfl_xor(v, 1);
        float cv = 1.0f, sv = 0.0f;
        if (mat < 2) { cv = cosT[sl * 64 + p]; sv = sinT[sl * 64 + p]; }
        if (!(lane & 1)) {
          float e_out = v * cv - vx * sv;        // a*c - b*s
          float o_out = v * sv + vx * cv;        // a*s + b*c
          u32 u = (u32)f2bf(e_out) | ((u32)f2bf(o_out) << 16);
          u32 elem = ((u32)((b * 16 + h) * 1024 + sl)) * 128 + (u32)d;
          reinterpret_cast<u32*>(outp)[elem >> 1] = u;
        }
      }
    }
  }
}

// ---------------- kernel B: causal flash attention -------------------------
// block = 4 waves x 16 q-rows (QBLK=64); KV tiles of 64.
// V staged TRANSPOSED in LDS: vT[dv][n ^ sw(dv)], sw = ((dv^(dv>>3))&7)<<3,
// so both the b16 scatter-writes (lanes vary dv>>3) and the bf8 fragment
// reads (lanes vary dv&7) spread 8 banks (2-way = free).
__global__ __launch_bounds__(256) void attn(
    const u16* __restrict__ qw, const u16* __restrict__ kw,
    const u16* __restrict__ vw, u16* __restrict__ yw) {
  __shared__ __align__(16) u16 k_lds[64 * 128];
  __shared__ __align__(16) u16 vT[128 * 64];
  __shared__ __align__(16) u16 p_lds[4][16 * 64];
  const int tid = threadIdx.x, lane = tid & 63, wid = tid >> 6;
  const int g = lane >> 4, c16 = lane & 15;
  const int qb = blockIdx.x;                      // 0..15
  const int bh = blockIdx.y;                      // 0..63
  const int b = bh >> 4, h = bh & 15;
  const u16* Qp = qw + (size_t)bh * SEQ * DH;
  const u16* Kp = kw + (size_t)bh * SEQ * DH;
  const u16* Vp = vw + (size_t)bh * SEQ * DH;
  const int qrow0 = qb * 64 + wid * 16;

  bf8_t qf[4];
#pragma unroll
  for (int c = 0; c < 4; ++c)
    qf[c] = *reinterpret_cast<const bf8_t*>(Qp + (size_t)(qrow0 + c16) * 128 + c * 32 + g * 8);

  f4_t yacc[8];
#pragma unroll
  for (int f = 0; f < 8; ++f) yacc[f] = (f4_t)0.0f;
  float m_run[4], l_run[4];
#pragma unroll
  for (int j = 0; j < 4; ++j) { m_run[j] = -3e38f; l_run[j] = 0.0f; }

  const float kscale = 0.08838834764831845f * 1.4426950408889634f; // (1/sqrt(128))*log2(e)
  const int T = qb + 1;

  for (int t = 0; t < T; ++t) {
    // ---- stage K (swizzled linear) and V^T (swizzled transpose) ----
#pragma unroll
    for (int i = 0; i < 4; ++i) {
      int idx = tid + i * 256;
      int n = idx >> 4, d0 = (idx & 15) * 8;
      bf8_t kv = *reinterpret_cast<const bf8_t*>(Kp + (size_t)(t * 64 + n) * 128 + d0);
      int hwk = ((n << 7) | d0) ^ ((n & 7) << 3);
      *reinterpret_cast<bf8_t*>(&k_lds[hwk]) = kv;
      bf8_t vv = *reinterpret_cast<const bf8_t*>(Vp + (size_t)(t * 64 + n) * 128 + d0);
#pragma unroll
      for (int e = 0; e < 8; ++e) {
        int dv = d0 + e;
        int sw = ((dv ^ (dv >> 3)) & 7) << 3;
        vT[dv * 64 + (n ^ sw)] = (u16)vv[e];
      }
    }
    __syncthreads();

    // ---- S = Q K^T ----
    f4_t sf[4];
#pragma unroll
    for (int nf = 0; nf < 4; ++nf) sf[nf] = (f4_t)0.0f;
#pragma unroll
    for (int nf = 0; nf < 4; ++nf) {
      int row = nf * 16 + c16;
#pragma unroll
      for (int c = 0; c < 4; ++c) {
        int hw = ((row << 7) | (c * 32 + g * 8)) ^ ((row & 7) << 3);
        bf8_t kf = *reinterpret_cast<const bf8_t*>(&k_lds[hw]);
        sf[nf] = __builtin_amdgcn_mfma_f32_16x16x32_bf16(qf[c], kf, sf[nf], 0, 0, 0);
      }
    }

    // ---- mask + online softmax (row q = qrow0+4g+j, col key = t*64+16nf+c16)
    float lm[4];
#pragma unroll
    for (int j = 0; j < 4; ++j) lm[j] = -3e38f;
#pragma unroll
    for (int nf = 0; nf < 4; ++nf) {
      int keyc = t * 64 + nf * 16 + c16;
#pragma unroll
      for (int j = 0; j < 4; ++j) {
        int qr = qrow0 + g * 4 + j;
        if (keyc > qr) sf[nf][j] = -3e38f;
        lm[j] = fmaxf(lm[j], sf[nf][j]);
      }
    }
#pragma unroll
    for (int j = 0; j < 4; ++j) {
      lm[j] = fmaxf(lm[j], __shfl_xor(lm[j], 1));
      lm[j] = fmaxf(lm[j], __shfl_xor(lm[j], 2));
      lm[j] = fmaxf(lm[j], __shfl_xor(lm[j], 4));
      lm[j] = fmaxf(lm[j], __shfl_xor(lm[j], 8));
    }
    float alpha[4], rs[4];
#pragma unroll
    for (int j = 0; j < 4; ++j) {
      float mn = fmaxf(m_run[j], lm[j]);
      alpha[j] = exp2f((m_run[j] - mn) * kscale);
      m_run[j] = mn;
      rs[j] = 0.0f;
    }
    // P (bf16-rounded so numerator/denominator stay consistent) -> p_lds
#pragma unroll
    for (int nf = 0; nf < 4; ++nf) {
#pragma unroll
      for (int j = 0; j < 4; ++j) {
        float p = exp2f((sf[nf][j] - m_run[j]) * kscale);
        u16 pb = f2bf(p);
        rs[j] += bf2f(pb);
        int q = g * 4 + j, n = nf * 16 + c16;
        int hw = ((q << 6) | n) ^ ((q & 7) << 3);
        p_lds[wid][hw] = pb;
      }
    }
#pragma unroll
    for (int j = 0; j < 4; ++j) {
      rs[j] += __shfl_xor(rs[j], 1);
      rs[j] += __shfl_xor(rs[j], 2);
      rs[j] += __shfl_xor(rs[j], 4);
      rs[j] += __shfl_xor(rs[j], 8);
      l_run[j] = l_run[j] * alpha[j] + rs[j];
    }
#pragma unroll
    for (int f = 0; f < 8; ++f)
#pragma unroll
      for (int j = 0; j < 4; ++j) yacc[f][j] *= alpha[j];

    __syncthreads();   // P visible within wave's LDS view

    // ---- y += P V : A = P[q=c16][k], B = V^T rows (dv) -> B[k=n][col=dv] ----
    bf8_t pa[2];
#pragma unroll
    for (int c = 0; c < 2; ++c) {
      int hw = ((c16 << 6) | (c * 32 + g * 8)) ^ ((c16 & 7) << 3);
      pa[c] = *reinterpret_cast<const bf8_t*>(&p_lds[wid][hw]);
    }
#pragma unroll
    for (int f = 0; f < 8; ++f) {
      int row = f * 16 + c16;
      int sw = ((row ^ (row >> 3)) & 7) << 3;
#pragma unroll
      for (int c = 0; c < 2; ++c) {
        int col = (c * 32 + g * 8) ^ sw;
        bf8_t vf = *reinterpret_cast<const bf8_t*>(&vT[row * 64 + col]);
        yacc[f] = __builtin_amdgcn_mfma_f32_16x16x32_bf16(pa[c], vf, yacc[f], 0, 0, 0);
      }
    }
    __syncthreads();   // protect k_lds/vT before next stage
  }

  // ---- epilogue: y /= l, store bf16 to y_ws[(b*S+s)*2048 + h*128 + dv] ----
  float rl[4];
#pragma unroll
  for (int j = 0; j < 4; ++j) rl[j] = 1.0f / l_run[j];
#pragma unroll
  for (int f = 0; f < 8; ++f) {
#pragma unroll
    for (int j = 0; j < 4; ++j) {
      float yv = yacc[f][j] * rl[j];
      float yn = __shfl_xor(yv, 1);
      if (!(lane & 1)) {
        int s_ = qrow0 + g * 4 + j;
        int dv = f * 16 + c16;
        u32 u = (u32)f2bf(yv) | ((u32)f2bf(yn) << 16);
        u32 elem = ((u32)(b * 1024 + s_)) * 2048 + (u32)(h * 128 + dv);
        reinterpret_cast<u32*>(yw)[elem >> 1] = u;
      }
    }
  }
}

// ---------------- kernel C: output projection (split-K=2) ------------------
__global__ __launch_bounds__(256) void oproj(
    const u16* __restrict__ yw, const float* __restrict__ wo,
    float* __restrict__ part) {
  __shared__ __align__(16) u16 a_lds[64 * 64];
  __shared__ __align__(16) u16 b_lds[64 * 64];
  const int tid = threadIdx.x, lane = tid & 63, wid = tid >> 6;
  const int g = lane >> 4, c16 = lane & 15;
  const int wr = wid >> 1, wc = wid & 1;
  const int m0 = blockIdx.x * 64, n0 = blockIdx.y * 64;
  const int z = blockIdx.z;
  float* po = part + (size_t)z * (MROWS * 128);
  f4_t acc[2][2];
#pragma unroll
  for (int a = 0; a < 2; ++a)
#pragma unroll
    for (int b = 0; b < 2; ++b) acc[a][b] = (f4_t)0.0f;

  for (int kt = z * 16; kt < z * 16 + 16; ++kt) {
    int kb = kt * 64;
#pragma unroll
    for (int i = 0; i < 2; ++i) {
      int idx = tid + i * 256;            // 0..511
      int row = idx >> 3, k0 = (idx & 7) * 8;
      bf8_t av = *reinterpret_cast<const bf8_t*>(yw + (size_t)(m0 + row) * 2048 + kb + k0);
      int hw = ((row << 6) | k0) ^ ((row & 7) << 3);
      *reinterpret_cast<bf8_t*>(&a_lds[hw]) = av;
      const f4_t* bs = reinterpret_cast<const f4_t*>(wo + (size_t)(n0 + row) * 2048 + kb + k0);
      f4_t blo = bs[0], bhi = bs[1];
      bf8_t bv;
#pragma unroll
      for (int j = 0; j < 4; ++j) { bv[j] = (short)f2bf(blo[j]); bv[4 + j] = (short)f2bf(bhi[j]); }
      *reinterpret_cast<bf8_t*>(&b_lds[hw]) = bv;
    }
    __syncthreads();
#pragma unroll
    for (int c = 0; c < 2; ++c) {
      bf8_t af[2], bf_[2];
#pragma unroll
      for (int fr = 0; fr < 2; ++fr) {
        int row = wr * 32 + fr * 16 + c16;
        int hw = ((row << 6) | (c * 32 + g * 8)) ^ ((row & 7) << 3);
        af[fr] = *reinterpret_cast<const bf8_t*>(&a_lds[hw]);
      }
#pragma unroll
      for (int fc = 0; fc < 2; ++fc) {
        int row = wc * 32 + fc * 16 + c16;
        int hw = ((row << 6) | (c * 32 + g * 8)) ^ ((row & 7) << 3);
        bf_[fc] = *reinterpret_cast<const bf8_t*>(&b_lds[hw]);
      }
#pragma unroll
      for (int fr = 0; fr < 2; ++fr)
#pragma unroll
        for (int fc = 0; fc < 2; ++fc)
          acc[fr][fc] = __builtin_amdgcn_mfma_f32_16x16x32_bf16(af[fr], bf_[fc], acc[fr][fc], 0, 0, 0);
    }
    __syncthreads();
  }
#pragma unroll
  for (int fr = 0; fr < 2; ++fr)
#pragma unroll
    for (int fc = 0; fc < 2; ++fc)
#pragma unroll
      for (int j = 0; j < 4; ++j) {
        int m = m0 + wr * 32 + fr * 16 + g * 4 + j;
        int e = n0 + wc * 32 + fc * 16 + c16;
        po[(size_t)m * 128 + e] = acc[fr][fc][j];
      }
}

__global__ __launch_bounds__(256) void oreduce(const float* __restrict__ part,
                                               float* __restrict__ out) {
  int i = blockIdx.x * 256 + threadIdx.x;     // 131072 float4 groups
  f4_t a = reinterpret_cast<const f4_t*>(part)[i];
  f4_t b = reinterpret_cast<const f4_t*>(part + (size_t)MROWS * 128)[i];
  reinterpret_cast<f4_t*>(out)[i] = a + b;
}

// ---------------------------------------------------------------------------
extern "C" void kernel_launch(void* const* d_in, const int* in_sizes, int n_in,
                              void* d_out, int out_size, void* d_ws, size_t ws_size,
                              hipStream_t stream) {
  const float* x  = (const float*)d_in[0];
  const float* wq = (const float*)d_in[1];
  const float* wk = (const float*)d_in[2];
  const float* wv = (const float*)d_in[3];
  const float* wo = (const float*)d_in[4];
  float* out = (float*)d_out;

  // ws layout: cos(256K) sin(256K) q(16M) k(16M) v(16M) y(16M) partials(4M)
  char* ws = (char*)d_ws;
  const size_t NEED = (512ull << 10) + 4ull * (16ull << 20) + (4ull << 20);
  if (ws_size < NEED) return;   // fail loud (output stays poisoned) rather than corrupt
  float* cosT = (float*)ws;
  float* sinT = cosT + 64 * 1024;
  u16* qws = (u16*)(ws + (512 << 10));
  u16* kws = qws + (8u << 20);
  u16* vws = kws + (8u << 20);
  u16* yws = vws + (8u << 20);
  float* part = (float*)(yws + (8u << 20));

  rope_tables<<<256, 256, 0, stream>>>(cosT, sinT);
  qkv_rope<<<dim3(64, 96), 256, 0, stream>>>(x, wq, wk, wv, cosT, sinT, qws, kws, vws);
  attn<<<dim3(16, 64), 256, 0, stream>>>(qws, kws, vws, yws);
  oproj<<<dim3(64, 2, 2), 256, 0, stream>>>(yws, wo, part);
  oreduce<<<512, 256, 0, stream>>>(part, out);
}